// Round 1
// baseline (461.172 us; speedup 1.0000x reference)
//
#include <hip/hip_runtime.h>

// ---------------- constants ----------------
constexpr int Bk = 4;
constexpr int Ck = 64;
constexpr int Lk = 9216;          // 96*96
constexpr int Nk = Bk * Lk;       // 36864 pixels
constexpr int Di = 128;           // spa inner dim
constexpr int XDP = 40;           // padded xdbl row (36 used)
constexpr int NCH = 128;          // scan chunks
constexpr int CSC = 72;           // chunk size (128*72 = 9216)

#define DEVINL __device__ __forceinline__

DEVINL float siluf(float v) { return v / (1.f + __expf(-v)); }
// matches jax.nn.softplus = max(x,0) + log1p(exp(-|x|))
DEVINL float softplusf(float v) { return fmaxf(v, 0.f) + log1pf(__expf(-fabsf(v))); }

// ---------------- K1: spatial in-projection ----------------
// xz[b, e, l] = sum_c x[b, c, l] * in_w[e, c]   (e = 0..255)
// grid (144, 4), block 256. grid.y selects 64 output rows.
__global__ __launch_bounds__(256) void k_inproj(const float* __restrict__ x,
                                                const float* __restrict__ in_w,
                                                float* __restrict__ xz) {
  __shared__ float ws[64 * 64];
  const int tid = threadIdx.x;
  const int eg = blockIdx.y;
  for (int i = tid; i < 4096; i += 256) ws[i] = in_w[eg * 4096 + i];
  __syncthreads();
  const int p = blockIdx.x * 256 + tid;
  const int b = p / Lk;
  const int l = p - b * Lk;
  float xr[64];
#pragma unroll
  for (int c = 0; c < 64; ++c) xr[c] = x[((size_t)(b * 64 + c)) * Lk + l];
  const float4* w4 = (const float4*)ws;
  for (int e = 0; e < 64; ++e) {
    float a0 = 0.f;
#pragma unroll
    for (int c4 = 0; c4 < 16; ++c4) {
      float4 wv = w4[e * 16 + c4];
      a0 += xr[c4 * 4 + 0] * wv.x + xr[c4 * 4 + 1] * wv.y +
            xr[c4 * 4 + 2] * wv.z + xr[c4 * 4 + 3] * wv.w;
    }
    xz[((size_t)(b * 256 + eg * 64 + e)) * Lk + l] = a0;
  }
}

// ---------------- K2: causal depthwise conv (k=4) + bias + silu ----------------
// grid (9, 512), block 256
__global__ __launch_bounds__(256) void k_conv(const float* __restrict__ xz,
                                              const float* __restrict__ cw,
                                              const float* __restrict__ cb,
                                              float* __restrict__ xc) {
  const int bd = blockIdx.y;           // b*128 + d
  const int d = bd & 127;
  const int b = bd >> 7;
  const int l4 = (blockIdx.x * 256 + threadIdx.x) * 4;
  const float* src = xz + ((size_t)(b * 256 + d)) * Lk;
  float4 cur = *(const float4*)(src + l4);
  float4 prev = make_float4(0.f, 0.f, 0.f, 0.f);
  if (l4 > 0) prev = *(const float4*)(src + l4 - 4);
  const float w0 = cw[d * 4 + 0], w1 = cw[d * 4 + 1], w2 = cw[d * 4 + 2],
              w3 = cw[d * 4 + 3], bb = cb[d];
  const float a1 = prev.y, a2 = prev.z, a3 = prev.w;
  const float a4 = cur.x, a5 = cur.y, a6 = cur.z, a7 = cur.w;
  float4 o;
  o.x = siluf(bb + w0 * a1 + w1 * a2 + w2 * a3 + w3 * a4);
  o.y = siluf(bb + w0 * a2 + w1 * a3 + w2 * a4 + w3 * a5);
  o.z = siluf(bb + w0 * a3 + w1 * a4 + w2 * a5 + w3 * a6);
  o.w = siluf(bb + w0 * a4 + w1 * a5 + w2 * a6 + w3 * a7);
  *(float4*)(xc + ((size_t)bd) * Lk + l4) = o;
}

// ---------------- K3: xdbl projection (128 -> 36), padded to 40 ----------------
// xdbl[(b*L+l)*40 + r] = sum_c xc[b,c,l] * x_w[r,c]
// block 256 = 64 px * 4 r-groups(9 r each); grid 576
__global__ __launch_bounds__(256) void k_xdbl(const float* __restrict__ xc,
                                              const float* __restrict__ xw,
                                              float* __restrict__ xdbl) {
  __shared__ float lw[36 * 128];
  __shared__ float lx[64 * 129];
  const int tid = threadIdx.x;
  for (int i = tid; i < 4608; i += 256) lw[i] = xw[i];
  const int p0 = blockIdx.x * 64;
  const int b = p0 / Lk;
  const int l0 = p0 - b * Lk;
  for (int i = tid; i < 8192; i += 256) {
    int c = i >> 6, pp = i & 63;
    lx[pp * 129 + c] = xc[((size_t)(b * 128 + c)) * Lk + l0 + pp];
  }
  __syncthreads();
  const int px = tid & 63;
  const int rg = tid >> 6;  // 0..3 -> rows rg*9..rg*9+8
  float acc[9];
#pragma unroll
  for (int j = 0; j < 9; ++j) acc[j] = 0.f;
  for (int c = 0; c < 128; ++c) {
    float xv = lx[px * 129 + c];
#pragma unroll
    for (int j = 0; j < 9; ++j) acc[j] += xv * lw[(rg * 9 + j) * 128 + c];
  }
  size_t rowo = ((size_t)(b * Lk + l0 + px)) * XDP + rg * 9;
#pragma unroll
  for (int j = 0; j < 9; ++j) xdbl[rowo + j] = acc[j];
}

// ---------------- K4a: scan pass 1 (per-chunk A-product and zero-init state) ----
// thread t: chunk c = t>>9, bd = t&511 (b = bd>>7, d = bd&127)
__global__ __launch_bounds__(256) void k_scan1(const float* __restrict__ xdbl,
                                               const float* __restrict__ xc,
                                               const float* __restrict__ Alog,
                                               const float* __restrict__ dtw,
                                               const float* __restrict__ dtb,
                                               float* __restrict__ Pb,
                                               float* __restrict__ Hb) {
  const int t = blockIdx.x * 256 + threadIdx.x;
  const int bd = t & 511;
  const int c = t >> 9;
  const int b = bd >> 7;
  const int d = bd & 127;
  float A[16];
#pragma unroll
  for (int n = 0; n < 16; ++n) A[n] = -__expf(Alog[d * 16 + n]);
  const float4 wv = *(const float4*)(dtw + d * 4);
  const float dbv = dtb[d];
  float h[16], P[16];
#pragma unroll
  for (int n = 0; n < 16; ++n) { h[n] = 0.f; P[n] = 1.f; }
  const float* xcp = xc + ((size_t)(b * 128 + d)) * Lk;
  const float* xrow = xdbl + ((size_t)b * Lk) * XDP;
  const int l0 = c * CSC;
  for (int l4 = l0; l4 < l0 + CSC; l4 += 4) {
    float4 xv = *(const float4*)(xcp + l4);
#pragma unroll
    for (int q = 0; q < 4; ++q) {
      const float4* row = (const float4*)(xrow + (size_t)(l4 + q) * XDP);
      float4 r0 = row[0];
      float dtv = softplusf(r0.x * wv.x + r0.y * wv.y + r0.z * wv.z + r0.w * wv.w + dbv);
      float xcv = (q == 0) ? xv.x : (q == 1) ? xv.y : (q == 2) ? xv.z : xv.w;
      float u = dtv * xcv;
      float4 B0 = row[1], B1 = row[2], B2 = row[3], B3 = row[4];
      float Bv[16] = {B0.x, B0.y, B0.z, B0.w, B1.x, B1.y, B1.z, B1.w,
                      B2.x, B2.y, B2.z, B2.w, B3.x, B3.y, B3.z, B3.w};
#pragma unroll
      for (int n = 0; n < 16; ++n) {
        float dA = __expf(dtv * A[n]);
        P[n] *= dA;
        h[n] = dA * h[n] + u * Bv[n];
      }
    }
  }
  size_t so = ((size_t)(c * 512 + bd)) * 16;
  float4* Pp = (float4*)(Pb + so);
  float4* Hp = (float4*)(Hb + so);
  Pp[0] = make_float4(P[0], P[1], P[2], P[3]);
  Pp[1] = make_float4(P[4], P[5], P[6], P[7]);
  Pp[2] = make_float4(P[8], P[9], P[10], P[11]);
  Pp[3] = make_float4(P[12], P[13], P[14], P[15]);
  Hp[0] = make_float4(h[0], h[1], h[2], h[3]);
  Hp[1] = make_float4(h[4], h[5], h[6], h[7]);
  Hp[2] = make_float4(h[8], h[9], h[10], h[11]);
  Hp[3] = make_float4(h[12], h[13], h[14], h[15]);
}

// ---------------- K4b: combine chunk states sequentially ----------------
// 8192 threads: u -> (bd = u>>4, n = u&15); idx = c*8192 + u (coalesced)
__global__ __launch_bounds__(256) void k_scan2(const float* __restrict__ Pb,
                                               const float* __restrict__ Hb,
                                               float* __restrict__ Ib) {
  const int u = blockIdx.x * 256 + threadIdx.x;
  float h = 0.f;
  for (int c = 0; c < NCH; ++c) {
    size_t idx = (size_t)c * 8192 + u;
    Ib[idx] = h;                     // init state entering chunk c
    h = Pb[idx] * h + Hb[idx];
  }
}

// ---------------- K4c: scan pass 3 (replay with init, emit y) ----------------
__global__ __launch_bounds__(256) void k_scan3(const float* __restrict__ xdbl,
                                               const float* __restrict__ xc,
                                               const float* __restrict__ Alog,
                                               const float* __restrict__ dtw,
                                               const float* __restrict__ dtb,
                                               const float* __restrict__ Ib,
                                               float* __restrict__ yi) {
  const int t = blockIdx.x * 256 + threadIdx.x;
  const int bd = t & 511;
  const int c = t >> 9;
  const int b = bd >> 7;
  const int d = bd & 127;
  float A[16];
#pragma unroll
  for (int n = 0; n < 16; ++n) A[n] = -__expf(Alog[d * 16 + n]);
  const float4 wv = *(const float4*)(dtw + d * 4);
  const float dbv = dtb[d];
  float h[16];
  {
    size_t so = ((size_t)(c * 512 + bd)) * 16;
    const float4* Ip = (const float4*)(Ib + so);
    float4 i0 = Ip[0], i1 = Ip[1], i2 = Ip[2], i3 = Ip[3];
    h[0] = i0.x; h[1] = i0.y; h[2] = i0.z; h[3] = i0.w;
    h[4] = i1.x; h[5] = i1.y; h[6] = i1.z; h[7] = i1.w;
    h[8] = i2.x; h[9] = i2.y; h[10] = i2.z; h[11] = i2.w;
    h[12] = i3.x; h[13] = i3.y; h[14] = i3.z; h[15] = i3.w;
  }
  const float* xcp = xc + ((size_t)(b * 128 + d)) * Lk;
  float* yp = yi + ((size_t)(b * 128 + d)) * Lk;
  const float* xrow = xdbl + ((size_t)b * Lk) * XDP;
  const int l0 = c * CSC;
  for (int l4 = l0; l4 < l0 + CSC; l4 += 4) {
    float4 xv = *(const float4*)(xcp + l4);
    float yo[4];
#pragma unroll
    for (int q = 0; q < 4; ++q) {
      const float4* row = (const float4*)(xrow + (size_t)(l4 + q) * XDP);
      float4 r0 = row[0];
      float dtv = softplusf(r0.x * wv.x + r0.y * wv.y + r0.z * wv.z + r0.w * wv.w + dbv);
      float xcv = (q == 0) ? xv.x : (q == 1) ? xv.y : (q == 2) ? xv.z : xv.w;
      float u = dtv * xcv;
      float4 B0 = row[1], B1 = row[2], B2 = row[3], B3 = row[4];
      float4 C0 = row[5], C1 = row[6], C2 = row[7], C3 = row[8];
      float Bv[16] = {B0.x, B0.y, B0.z, B0.w, B1.x, B1.y, B1.z, B1.w,
                      B2.x, B2.y, B2.z, B2.w, B3.x, B3.y, B3.z, B3.w};
      float Cv[16] = {C0.x, C0.y, C0.z, C0.w, C1.x, C1.y, C1.z, C1.w,
                      C2.x, C2.y, C2.z, C2.w, C3.x, C3.y, C3.z, C3.w};
      float acc = 0.f;
#pragma unroll
      for (int n = 0; n < 16; ++n) {
        float dA = __expf(dtv * A[n]);
        h[n] = dA * h[n] + u * Bv[n];
        acc += h[n] * Cv[n];
      }
      yo[q] = acc;
    }
    *(float4*)(yp + l4) = make_float4(yo[0], yo[1], yo[2], yo[3]);
  }
}

// ---------------- K5: gate + out-projection (128 -> 64) ----------------
// grid (144, 2): grid.y = 32 output rows each
__global__ __launch_bounds__(256) void k_gateout(const float* __restrict__ yi,
                                                 const float* __restrict__ xc,
                                                 const float* __restrict__ xz,
                                                 const float* __restrict__ Dp,
                                                 const float* __restrict__ ow,
                                                 float* __restrict__ spa_y) {
  __shared__ float ws[32 * 128];
  __shared__ float lD[128];
  const int tid = threadIdx.x;
  const int eh = blockIdx.y;
  for (int i = tid; i < 4096; i += 256) ws[i] = ow[eh * 4096 + i];
  if (tid < 128) lD[tid] = Dp[tid];
  __syncthreads();
  const int p = blockIdx.x * 256 + tid;
  const int b = p / Lk;
  const int l = p - b * Lk;
  float g[128];
#pragma unroll
  for (int d = 0; d < 128; ++d) {
    float yv = yi[((size_t)(b * 128 + d)) * Lk + l];
    float xcv = xc[((size_t)(b * 128 + d)) * Lk + l];
    float zv = xz[((size_t)(b * 256 + 128 + d)) * Lk + l];
    g[d] = (yv + xcv * lD[d]) * siluf(zv);
  }
  const float4* w4 = (const float4*)ws;
  for (int e = 0; e < 32; ++e) {
    float acc = 0.f;
#pragma unroll
    for (int c4 = 0; c4 < 32; ++c4) {
      float4 wv = w4[e * 32 + c4];
      acc += g[c4 * 4 + 0] * wv.x + g[c4 * 4 + 1] * wv.y +
             g[c4 * 4 + 2] * wv.z + g[c4 * 4 + 3] * wv.w;
    }
    spa_y[((size_t)(b * 64 + eh * 32 + e)) * Lk + l] = acc;
  }
}

// ---------------- K8: full spectral mamba, fused per-pixel ----------------
// block 256 = 16 px * 16 channels; grid 2304
constexpr int XT = 20;    // lds t-stride
constexpr int XPX = 164;  // lds px-stride (8*20+4)
__global__ __launch_bounds__(256) void k_spe(const float* __restrict__ x,
                                             const float* __restrict__ in_w,
                                             const float* __restrict__ cw,
                                             const float* __restrict__ cb,
                                             const float* __restrict__ xw,
                                             const float* __restrict__ dtw,
                                             const float* __restrict__ dtb,
                                             const float* __restrict__ Alog,
                                             const float* __restrict__ Dp,
                                             const float* __restrict__ ow,
                                             float* __restrict__ spe_y) {
  __shared__ float lx[16 * 68];
  __shared__ float lxw[33 * 20];
  __shared__ float lB[16 * XPX];
  __shared__ float lC[16 * XPX];
  __shared__ float lxc[16 * XPX];
  __shared__ float low[128];
  const int tid = threadIdx.x;
  const int px = tid >> 4;
  const int d = tid & 15;
  const int gp0 = blockIdx.x * 16;
  const int b = gp0 / Lk;
  const int l0 = gp0 - b * Lk;
  for (int i = tid; i < 1024; i += 256) {
    int c = i >> 4, pp = i & 15;
    lx[pp * 68 + c] = x[((size_t)(b * 64 + c)) * Lk + l0 + pp];
  }
  for (int i = tid; i < 528; i += 256) lxw[(i / 16) * 20 + (i % 16)] = xw[i];
  if (tid < 128) low[tid] = ow[tid];
  __syncthreads();
  float riw[8], riz[8];
#pragma unroll
  for (int g = 0; g < 8; ++g) {
    riw[g] = in_w[d * 8 + g];
    riz[g] = in_w[(16 + d) * 8 + g];
  }
  const float w0 = cw[d * 4 + 0], w1 = cw[d * 4 + 1], w2 = cw[d * 4 + 2],
              w3 = cw[d * 4 + 3], cbv = cb[d];
  const float dtwv = dtw[d], dtbv = dtb[d], Dv = Dp[d];
  float A2[16];
#pragma unroll
  for (int n = 0; n < 16; ++n) A2[n] = -__expf(Alog[d * 16 + n]);
  // in-projection + z-gate
  float xcr[8], zq[8];
#pragma unroll
  for (int tt = 0; tt < 8; ++tt) {
    float a = 0.f, zz = 0.f;
#pragma unroll
    for (int g = 0; g < 8; ++g) {
      float xv = lx[px * 68 + tt * 8 + g];
      a += xv * riw[g];
      zz += xv * riz[g];
    }
    xcr[tt] = a;
    zq[tt] = siluf(zz);
  }
  // causal conv k=4 + silu
  float xcq[8];
#pragma unroll
  for (int tt = 0; tt < 8; ++tt) {
    float s = cbv + w3 * xcr[tt];
    if (tt >= 1) s += w2 * xcr[tt - 1];
    if (tt >= 2) s += w1 * xcr[tt - 2];
    if (tt >= 3) s += w0 * xcr[tt - 3];
    xcq[tt] = siluf(s);
  }
#pragma unroll
  for (int tt = 0; tt < 8; ++tt) lxc[px * XPX + tt * XT + d] = xcq[tt];
  __syncthreads();
  // B, C (thread d computes state-index n = d), dt
  float dtv[8];
#pragma unroll
  for (int tt = 0; tt < 8; ++tt) {
    float sB = 0.f, sC = 0.f, ss = 0.f;
#pragma unroll
    for (int dd = 0; dd < 16; ++dd) {
      float xv = lxc[px * XPX + tt * XT + dd];
      ss += xv * lxw[dd];
      sB += xv * lxw[(1 + d) * 20 + dd];
      sC += xv * lxw[(17 + d) * 20 + dd];
    }
    lB[px * XPX + tt * XT + d] = sB;
    lC[px * XPX + tt * XT + d] = sC;
    dtv[tt] = softplusf(ss * dtwv + dtbv);
  }
  __syncthreads();
  // selective scan over 8 tokens
  float h[16];
#pragma unroll
  for (int n = 0; n < 16; ++n) h[n] = 0.f;
  float yv[8];
#pragma unroll
  for (int tt = 0; tt < 8; ++tt) {
    float u = dtv[tt] * xcq[tt];
    float acc = 0.f;
#pragma unroll
    for (int n = 0; n < 16; ++n) {
      float dA = __expf(dtv[tt] * A2[n]);
      h[n] = dA * h[n] + u * lB[px * XPX + tt * XT + n];
      acc += h[n] * lC[px * XPX + tt * XT + n];
    }
    yv[tt] = (acc + xcq[tt] * Dv) * zq[tt];
  }
#pragma unroll
  for (int tt = 0; tt < 8; ++tt) lxc[px * XPX + tt * XT + d] = yv[tt];
  __syncthreads();
  // out-projection 16 -> 8; thread handles outputs o = d*4 .. d*4+3
#pragma unroll
  for (int k = 0; k < 4; ++k) {
    int o = d * 4 + k;
    int tt = o >> 3, e = o & 7;
    float acc = 0.f;
#pragma unroll
    for (int dd = 0; dd < 16; ++dd)
      acc += lxc[px * XPX + tt * XT + dd] * low[e * 16 + dd];
    spe_y[((size_t)(b * 64 + tt * 8 + e)) * Lk + l0 + px] = acc;
  }
}

// ---------------- K6a: GN partial sums ----------------
// grid 256: gid = bx>>3 (32 groups: branch*16 + b*4 + g), part = bx&7
__global__ __launch_bounds__(256) void k_stats1(const float* __restrict__ spa_y,
                                                const float* __restrict__ spe_y,
                                                float* __restrict__ part) {
  const int gid = blockIdx.x >> 3;
  const int pi = blockIdx.x & 7;
  const int branch = gid >> 4;
  const int rem = gid & 15;
  const int b = rem >> 2;
  const int g = rem & 3;
  const float* src = (branch ? spe_y : spa_y) +
                     ((size_t)(b * 64 + g * 16)) * Lk + (size_t)pi * 18432;
  float s = 0.f, sq = 0.f;
  for (int i = 0; i < 18; ++i) {
    float4 v = *(const float4*)(src + (i * 256 + threadIdx.x) * 4);
    s += v.x + v.y + v.z + v.w;
    sq += v.x * v.x + v.y * v.y + v.z * v.z + v.w * v.w;
  }
  for (int off = 32; off > 0; off >>= 1) {
    s += __shfl_down(s, off);
    sq += __shfl_down(sq, off);
  }
  __shared__ float red[8];
  const int wid = threadIdx.x >> 6;
  if ((threadIdx.x & 63) == 0) { red[wid * 2] = s; red[wid * 2 + 1] = sq; }
  __syncthreads();
  if (threadIdx.x == 0) {
    s = red[0] + red[2] + red[4] + red[6];
    sq = red[1] + red[3] + red[5] + red[7];
    part[blockIdx.x * 2] = s;
    part[blockIdx.x * 2 + 1] = sq;
  }
}

// ---------------- K6b: finalize stats + fuse softmax ----------------
__global__ void k_stats2(const float* __restrict__ part, const float* __restrict__ fw,
                         float* __restrict__ stats) {
  const int t = threadIdx.x;
  if (t < 32) {
    float s = 0.f, sq = 0.f;
    for (int pi = 0; pi < 8; ++pi) {
      s += part[(t * 8 + pi) * 2];
      sq += part[(t * 8 + pi) * 2 + 1];
    }
    const float inv = 1.f / 147456.f;
    float m = s * inv;
    float var = sq * inv - m * m;
    stats[t * 2] = m;
    stats[t * 2 + 1] = 1.f / sqrtf(var + 1e-5f);
  } else if (t == 32) {
    float e0 = __expf(fw[0]), e1 = __expf(fw[1]);
    float inv = 1.f / (e0 + e1);
    stats[64] = e0 * inv;
    stats[65] = e1 * inv;
  }
}

// ---------------- K7: GN-affine + silu (both branches) + fusion + residual ----
// grid 256 (one block per (b,c) row), block 256
__global__ __launch_bounds__(256) void k_final(const float* __restrict__ spa_y,
                                               const float* __restrict__ spe_y,
                                               const float* __restrict__ x,
                                               const float* __restrict__ gga,
                                               const float* __restrict__ gba,
                                               const float* __restrict__ gge,
                                               const float* __restrict__ gbe,
                                               const float* __restrict__ stats,
                                               float* __restrict__ out) {
  const int bc = blockIdx.x;
  const int b = bc >> 6;
  const int c = bc & 63;
  const int g = c >> 4;
  const float w0 = stats[64], w1 = stats[65];
  const float m0 = stats[(b * 4 + g) * 2], r0 = stats[(b * 4 + g) * 2 + 1];
  const float m1 = stats[(16 + b * 4 + g) * 2], r1 = stats[(16 + b * 4 + g) * 2 + 1];
  const float ka = r0 * gga[c], ca = gba[c] - m0 * ka;
  const float ke = r1 * gge[c], ce = gbe[c] - m1 * ke;
  const size_t base = (size_t)bc * Lk;
  for (int i = 0; i < 9; ++i) {
    const int idx = (i * 256 + threadIdx.x) * 4;
    float4 a = *(const float4*)(spa_y + base + idx);
    float4 e = *(const float4*)(spe_y + base + idx);
    float4 xv = *(const float4*)(x + base + idx);
    float4 o;
    o.x = xv.x + w0 * siluf(a.x * ka + ca) + w1 * siluf(e.x * ke + ce);
    o.y = xv.y + w0 * siluf(a.y * ka + ca) + w1 * siluf(e.y * ke + ce);
    o.z = xv.z + w0 * siluf(a.z * ka + ca) + w1 * siluf(e.z * ke + ce);
    o.w = xv.w + w0 * siluf(a.w * ka + ca) + w1 * siluf(e.w * ke + ce);
    *(float4*)(out + base + idx) = o;
  }
}

// ---------------- launch ----------------
extern "C" void kernel_launch(void* const* d_in, const int* in_sizes, int n_in,
                              void* d_out, int out_size, void* d_ws, size_t ws_size,
                              hipStream_t stream) {
  (void)in_sizes; (void)n_in; (void)out_size; (void)ws_size;
  const float* x = (const float*)d_in[0];
  const float* spa_in_w = (const float*)d_in[1];
  const float* spa_conv_w = (const float*)d_in[2];
  const float* spa_conv_b = (const float*)d_in[3];
  const float* spa_x_w = (const float*)d_in[4];
  const float* spa_dt_w = (const float*)d_in[5];
  const float* spa_dt_b = (const float*)d_in[6];
  const float* spa_A_log = (const float*)d_in[7];
  const float* spa_D = (const float*)d_in[8];
  const float* spa_out_w = (const float*)d_in[9];
  const float* spa_gn_g = (const float*)d_in[10];
  const float* spa_gn_b = (const float*)d_in[11];
  const float* spe_in_w = (const float*)d_in[12];
  const float* spe_conv_w = (const float*)d_in[13];
  const float* spe_conv_b = (const float*)d_in[14];
  const float* spe_x_w = (const float*)d_in[15];
  const float* spe_dt_w = (const float*)d_in[16];
  const float* spe_dt_b = (const float*)d_in[17];
  const float* spe_A_log = (const float*)d_in[18];
  const float* spe_D = (const float*)d_in[19];
  const float* spe_out_w = (const float*)d_in[20];
  const float* spe_gn_g = (const float*)d_in[21];
  const float* spe_gn_b = (const float*)d_in[22];
  const float* fuse_w = (const float*)d_in[23];
  float* out = (float*)d_out;
  float* ws = (float*)d_ws;

  float* xz = ws;                         // 4*256*9216 = 9437184
  float* xc = xz + 9437184;               // 4718592
  float* xdbl = xc + 4718592;             // 4*9216*40 = 1474560
  float* yi = xdbl + 1474560;             // 4718592
  float* Pb = yi + 4718592;               // 1048576
  float* Hb = Pb + 1048576;               // 1048576
  float* Ib = Hb + 1048576;               // 1048576
  float* spa_y = Ib + 1048576;            // 2359296
  float* spe_y = spa_y + 2359296;         // 2359296
  float* part = spe_y + 2359296;          // 512
  float* stats = part + 512;              // 66

  k_inproj<<<dim3(144, 4), 256, 0, stream>>>(x, spa_in_w, xz);
  k_conv<<<dim3(9, 512), 256, 0, stream>>>(xz, spa_conv_w, spa_conv_b, xc);
  k_xdbl<<<576, 256, 0, stream>>>(xc, spa_x_w, xdbl);
  k_scan1<<<256, 256, 0, stream>>>(xdbl, xc, spa_A_log, spa_dt_w, spa_dt_b, Pb, Hb);
  k_scan2<<<32, 256, 0, stream>>>(Pb, Hb, Ib);
  k_scan3<<<256, 256, 0, stream>>>(xdbl, xc, spa_A_log, spa_dt_w, spa_dt_b, Ib, yi);
  k_gateout<<<dim3(144, 2), 256, 0, stream>>>(yi, xc, xz, spa_D, spa_out_w, spa_y);
  k_spe<<<2304, 256, 0, stream>>>(x, spe_in_w, spe_conv_w, spe_conv_b, spe_x_w,
                                  spe_dt_w, spe_dt_b, spe_A_log, spe_D, spe_out_w,
                                  spe_y);
  k_stats1<<<256, 256, 0, stream>>>(spa_y, spe_y, part);
  k_stats2<<<1, 64, 0, stream>>>(part, fuse_w, stats);
  k_final<<<256, 256, 0, stream>>>(spa_y, spe_y, x, spa_gn_g, spa_gn_b,
                                   spe_gn_g, spe_gn_b, stats, out);
}

// Round 2
// 307.445 us; speedup vs baseline: 1.5000x; 1.5000x over previous
//
#include <hip/hip_runtime.h>

// ---------------- constants ----------------
constexpr int Bk = 4;
constexpr int Ck = 64;
constexpr int Lk = 9216;          // 96*96
constexpr int Nk = Bk * Lk;       // 36864 pixels
constexpr int Di = 128;           // spa inner dim
constexpr int XDP = 40;           // padded xdbl row (36 used)
constexpr int NCH = 128;          // scan chunks
constexpr int CSC = 72;           // chunk size (128*72 = 9216)

#define DEVINL __device__ __forceinline__

DEVINL float siluf(float v) { return v / (1.f + __expf(-v)); }
// matches jax.nn.softplus = max(x,0) + log1p(exp(-|x|))
DEVINL float softplusf(float v) { return fmaxf(v, 0.f) + log1pf(__expf(-fabsf(v))); }

// ---------------- K1: spatial in-projection ----------------
// xz[b, e, l] = sum_c x[b, c, l] * in_w[e, c]   (e = 0..255)
// grid (144, 4), block 256. grid.y selects 64 output rows.
__global__ __launch_bounds__(256) void k_inproj(const float* __restrict__ x,
                                                const float* __restrict__ in_w,
                                                float* __restrict__ xz) {
  __shared__ float ws[64 * 64];
  const int tid = threadIdx.x;
  const int eg = blockIdx.y;
  for (int i = tid; i < 4096; i += 256) ws[i] = in_w[eg * 4096 + i];
  __syncthreads();
  const int p = blockIdx.x * 256 + tid;
  const int b = p / Lk;
  const int l = p - b * Lk;
  float xr[64];
#pragma unroll
  for (int c = 0; c < 64; ++c) xr[c] = x[((size_t)(b * 64 + c)) * Lk + l];
  const float4* w4 = (const float4*)ws;
  for (int e = 0; e < 64; ++e) {
    float a0 = 0.f;
#pragma unroll
    for (int c4 = 0; c4 < 16; ++c4) {
      float4 wv = w4[e * 16 + c4];
      a0 += xr[c4 * 4 + 0] * wv.x + xr[c4 * 4 + 1] * wv.y +
            xr[c4 * 4 + 2] * wv.z + xr[c4 * 4 + 3] * wv.w;
    }
    xz[((size_t)(b * 256 + eg * 64 + e)) * Lk + l] = a0;
  }
}

// ---------------- K2: causal depthwise conv (k=4) + bias + silu ----------------
// grid (9, 512), block 256
__global__ __launch_bounds__(256) void k_conv(const float* __restrict__ xz,
                                              const float* __restrict__ cw,
                                              const float* __restrict__ cb,
                                              float* __restrict__ xc) {
  const int bd = blockIdx.y;           // b*128 + d
  const int d = bd & 127;
  const int b = bd >> 7;
  const int l4 = (blockIdx.x * 256 + threadIdx.x) * 4;
  const float* src = xz + ((size_t)(b * 256 + d)) * Lk;
  float4 cur = *(const float4*)(src + l4);
  float4 prev = make_float4(0.f, 0.f, 0.f, 0.f);
  if (l4 > 0) prev = *(const float4*)(src + l4 - 4);
  const float w0 = cw[d * 4 + 0], w1 = cw[d * 4 + 1], w2 = cw[d * 4 + 2],
              w3 = cw[d * 4 + 3], bb = cb[d];
  const float a1 = prev.y, a2 = prev.z, a3 = prev.w;
  const float a4 = cur.x, a5 = cur.y, a6 = cur.z, a7 = cur.w;
  float4 o;
  o.x = siluf(bb + w0 * a1 + w1 * a2 + w2 * a3 + w3 * a4);
  o.y = siluf(bb + w0 * a2 + w1 * a3 + w2 * a4 + w3 * a5);
  o.z = siluf(bb + w0 * a3 + w1 * a4 + w2 * a5 + w3 * a6);
  o.w = siluf(bb + w0 * a4 + w1 * a5 + w2 * a6 + w3 * a7);
  *(float4*)(xc + ((size_t)bd) * Lk + l4) = o;
}

// ---------------- K3: xdbl projection (128 -> 36), padded to 40 ----------------
// xdbl[(b*L+l)*40 + r] = sum_c xc[b,c,l] * x_w[r,c]
// block 256 = 64 px * 4 r-groups(9 r each); grid 576
__global__ __launch_bounds__(256) void k_xdbl(const float* __restrict__ xc,
                                              const float* __restrict__ xw,
                                              float* __restrict__ xdbl) {
  __shared__ float lw[36 * 128];
  __shared__ float lx[64 * 129];
  const int tid = threadIdx.x;
  for (int i = tid; i < 4608; i += 256) lw[i] = xw[i];
  const int p0 = blockIdx.x * 64;
  const int b = p0 / Lk;
  const int l0 = p0 - b * Lk;
  for (int i = tid; i < 8192; i += 256) {
    int c = i >> 6, pp = i & 63;
    lx[pp * 129 + c] = xc[((size_t)(b * 128 + c)) * Lk + l0 + pp];
  }
  __syncthreads();
  const int px = tid & 63;
  const int rg = tid >> 6;  // 0..3 -> rows rg*9..rg*9+8
  float acc[9];
#pragma unroll
  for (int j = 0; j < 9; ++j) acc[j] = 0.f;
  for (int c = 0; c < 128; ++c) {
    float xv = lx[px * 129 + c];
#pragma unroll
    for (int j = 0; j < 9; ++j) acc[j] += xv * lw[(rg * 9 + j) * 128 + c];
  }
  size_t rowo = ((size_t)(b * Lk + l0 + px)) * XDP + rg * 9;
#pragma unroll
  for (int j = 0; j < 9; ++j) xdbl[rowo + j] = acc[j];
}

// ---------------- K4a: scan pass 1 (per-chunk A-product and zero-init state) ----
// thread t: chunk c = t>>9, bd = t&511 (b = bd>>7, d = bd&127)
__global__ __launch_bounds__(256) void k_scan1(const float* __restrict__ xdbl,
                                               const float* __restrict__ xc,
                                               const float* __restrict__ Alog,
                                               const float* __restrict__ dtw,
                                               const float* __restrict__ dtb,
                                               float* __restrict__ Pb,
                                               float* __restrict__ Hb) {
  const int t = blockIdx.x * 256 + threadIdx.x;
  const int bd = t & 511;
  const int c = t >> 9;
  const int b = bd >> 7;
  const int d = bd & 127;
  float A[16];
#pragma unroll
  for (int n = 0; n < 16; ++n) A[n] = -__expf(Alog[d * 16 + n]);
  const float4 wv = *(const float4*)(dtw + d * 4);
  const float dbv = dtb[d];
  float h[16], P[16];
#pragma unroll
  for (int n = 0; n < 16; ++n) { h[n] = 0.f; P[n] = 1.f; }
  const float* xcp = xc + ((size_t)(b * 128 + d)) * Lk;
  const float* xrow = xdbl + ((size_t)b * Lk) * XDP;
  const int l0 = c * CSC;
  for (int l4 = l0; l4 < l0 + CSC; l4 += 4) {
    float4 xv = *(const float4*)(xcp + l4);
#pragma unroll
    for (int q = 0; q < 4; ++q) {
      const float4* row = (const float4*)(xrow + (size_t)(l4 + q) * XDP);
      float4 r0 = row[0];
      float dtv = softplusf(r0.x * wv.x + r0.y * wv.y + r0.z * wv.z + r0.w * wv.w + dbv);
      float xcv = (q == 0) ? xv.x : (q == 1) ? xv.y : (q == 2) ? xv.z : xv.w;
      float u = dtv * xcv;
      float4 B0 = row[1], B1 = row[2], B2 = row[3], B3 = row[4];
      float Bv[16] = {B0.x, B0.y, B0.z, B0.w, B1.x, B1.y, B1.z, B1.w,
                      B2.x, B2.y, B2.z, B2.w, B3.x, B3.y, B3.z, B3.w};
#pragma unroll
      for (int n = 0; n < 16; ++n) {
        float dA = __expf(dtv * A[n]);
        P[n] *= dA;
        h[n] = dA * h[n] + u * Bv[n];
      }
    }
  }
  size_t so = ((size_t)(c * 512 + bd)) * 16;
  float4* Pp = (float4*)(Pb + so);
  float4* Hp = (float4*)(Hb + so);
  Pp[0] = make_float4(P[0], P[1], P[2], P[3]);
  Pp[1] = make_float4(P[4], P[5], P[6], P[7]);
  Pp[2] = make_float4(P[8], P[9], P[10], P[11]);
  Pp[3] = make_float4(P[12], P[13], P[14], P[15]);
  Hp[0] = make_float4(h[0], h[1], h[2], h[3]);
  Hp[1] = make_float4(h[4], h[5], h[6], h[7]);
  Hp[2] = make_float4(h[8], h[9], h[10], h[11]);
  Hp[3] = make_float4(h[12], h[13], h[14], h[15]);
}

// ---------------- K4b: combine chunk states sequentially ----------------
// 8192 threads: u -> (bd = u>>4, n = u&15); idx = c*8192 + u (coalesced)
__global__ __launch_bounds__(256) void k_scan2(const float* __restrict__ Pb,
                                               const float* __restrict__ Hb,
                                               float* __restrict__ Ib) {
  const int u = blockIdx.x * 256 + threadIdx.x;
  float h = 0.f;
  for (int c = 0; c < NCH; ++c) {
    size_t idx = (size_t)c * 8192 + u;
    Ib[idx] = h;                     // init state entering chunk c
    h = Pb[idx] * h + Hb[idx];
  }
}

// ---------------- K4c: scan pass 3 (replay with init, emit gated g) ----------
// g[b,d,l] = (y + xc*D[d]) * silu(z)   -- gate fused here
__global__ __launch_bounds__(256) void k_scan3(const float* __restrict__ xdbl,
                                               const float* __restrict__ xc,
                                               const float* __restrict__ xz,
                                               const float* __restrict__ Alog,
                                               const float* __restrict__ dtw,
                                               const float* __restrict__ dtb,
                                               const float* __restrict__ Dp,
                                               const float* __restrict__ Ib,
                                               float* __restrict__ gi) {
  const int t = blockIdx.x * 256 + threadIdx.x;
  const int bd = t & 511;
  const int c = t >> 9;
  const int b = bd >> 7;
  const int d = bd & 127;
  float A[16];
#pragma unroll
  for (int n = 0; n < 16; ++n) A[n] = -__expf(Alog[d * 16 + n]);
  const float4 wv = *(const float4*)(dtw + d * 4);
  const float dbv = dtb[d];
  const float Dv = Dp[d];
  float h[16];
  {
    size_t so = ((size_t)(c * 512 + bd)) * 16;
    const float4* Ip = (const float4*)(Ib + so);
    float4 i0 = Ip[0], i1 = Ip[1], i2 = Ip[2], i3 = Ip[3];
    h[0] = i0.x; h[1] = i0.y; h[2] = i0.z; h[3] = i0.w;
    h[4] = i1.x; h[5] = i1.y; h[6] = i1.z; h[7] = i1.w;
    h[8] = i2.x; h[9] = i2.y; h[10] = i2.z; h[11] = i2.w;
    h[12] = i3.x; h[13] = i3.y; h[14] = i3.z; h[15] = i3.w;
  }
  const float* xcp = xc + ((size_t)(b * 128 + d)) * Lk;
  const float* zp = xz + ((size_t)(b * 256 + 128 + d)) * Lk;
  float* gp = gi + ((size_t)(b * 128 + d)) * Lk;
  const float* xrow = xdbl + ((size_t)b * Lk) * XDP;
  const int l0 = c * CSC;
  for (int l4 = l0; l4 < l0 + CSC; l4 += 4) {
    float4 xv = *(const float4*)(xcp + l4);
    float4 zv = *(const float4*)(zp + l4);
    float yo[4];
#pragma unroll
    for (int q = 0; q < 4; ++q) {
      const float4* row = (const float4*)(xrow + (size_t)(l4 + q) * XDP);
      float4 r0 = row[0];
      float dtv = softplusf(r0.x * wv.x + r0.y * wv.y + r0.z * wv.z + r0.w * wv.w + dbv);
      float xcv = (q == 0) ? xv.x : (q == 1) ? xv.y : (q == 2) ? xv.z : xv.w;
      float zvv = (q == 0) ? zv.x : (q == 1) ? zv.y : (q == 2) ? zv.z : zv.w;
      float u = dtv * xcv;
      float4 B0 = row[1], B1 = row[2], B2 = row[3], B3 = row[4];
      float4 C0 = row[5], C1 = row[6], C2 = row[7], C3 = row[8];
      float Bv[16] = {B0.x, B0.y, B0.z, B0.w, B1.x, B1.y, B1.z, B1.w,
                      B2.x, B2.y, B2.z, B2.w, B3.x, B3.y, B3.z, B3.w};
      float Cv[16] = {C0.x, C0.y, C0.z, C0.w, C1.x, C1.y, C1.z, C1.w,
                      C2.x, C2.y, C2.z, C2.w, C3.x, C3.y, C3.z, C3.w};
      float acc = 0.f;
#pragma unroll
      for (int n = 0; n < 16; ++n) {
        float dA = __expf(dtv * A[n]);
        h[n] = dA * h[n] + u * Bv[n];
        acc += h[n] * Cv[n];
      }
      yo[q] = (acc + xcv * Dv) * siluf(zvv);
    }
    *(float4*)(gp + l4) = make_float4(yo[0], yo[1], yo[2], yo[3]);
  }
}

// ---------------- K5: out-projection (128 -> 64), LDS-staged ----------------
// block 256 = 64 px * 4 wave e-groups (16 e each); grid 576
__global__ __launch_bounds__(256) void k_out(const float* __restrict__ gi,
                                             const float* __restrict__ ow,
                                             float* __restrict__ spa_y) {
  __shared__ float lg[64 * 129];    // [px][c] padded
  __shared__ float lwT[128 * 68];   // [c][e] padded, float4-aligned
  const int tid = threadIdx.x;
  const int p0 = blockIdx.x * 64;
  const int b = p0 / Lk;
  const int l0 = p0 - b * Lk;
  for (int i = tid; i < 8192; i += 256) {
    int d = i >> 6, px = i & 63;
    lg[px * 129 + d] = gi[((size_t)(b * 128 + d)) * Lk + l0 + px];
  }
  for (int i = tid; i < 8192; i += 256) {
    int e = i >> 7, c = i & 127;
    lwT[c * 68 + e] = ow[i];
  }
  __syncthreads();
  const int px = tid & 63;
  const int eg = tid >> 6;          // wave-uniform
  float acc[16];
#pragma unroll
  for (int j = 0; j < 16; ++j) acc[j] = 0.f;
  const float4* w4 = (const float4*)lwT;
  for (int c = 0; c < 128; ++c) {
    float xv = lg[px * 129 + c];
    // broadcast reads: all 64 lanes of the wave share eg
    float4 wa = w4[c * 17 + eg * 4 + 0];
    float4 wb = w4[c * 17 + eg * 4 + 1];
    float4 wc = w4[c * 17 + eg * 4 + 2];
    float4 wd = w4[c * 17 + eg * 4 + 3];
    acc[0] += xv * wa.x;  acc[1] += xv * wa.y;  acc[2] += xv * wa.z;  acc[3] += xv * wa.w;
    acc[4] += xv * wb.x;  acc[5] += xv * wb.y;  acc[6] += xv * wb.z;  acc[7] += xv * wb.w;
    acc[8] += xv * wc.x;  acc[9] += xv * wc.y;  acc[10] += xv * wc.z; acc[11] += xv * wc.w;
    acc[12] += xv * wd.x; acc[13] += xv * wd.y; acc[14] += xv * wd.z; acc[15] += xv * wd.w;
  }
#pragma unroll
  for (int j = 0; j < 16; ++j)
    spa_y[((size_t)(b * 64 + eg * 16 + j)) * Lk + l0 + px] = acc[j];
}

// ---------------- K8: full spectral mamba, fused per-pixel ----------------
// block 256 = 16 px * 16 channels; grid 2304
constexpr int XT = 20;    // lds t-stride
constexpr int XPX = 164;  // lds px-stride (8*20+4)
__global__ __launch_bounds__(256) void k_spe(const float* __restrict__ x,
                                             const float* __restrict__ in_w,
                                             const float* __restrict__ cw,
                                             const float* __restrict__ cb,
                                             const float* __restrict__ xw,
                                             const float* __restrict__ dtw,
                                             const float* __restrict__ dtb,
                                             const float* __restrict__ Alog,
                                             const float* __restrict__ Dp,
                                             const float* __restrict__ ow,
                                             float* __restrict__ spe_y) {
  __shared__ float lx[16 * 68];
  __shared__ float lxw[33 * 20];
  __shared__ float lB[16 * XPX];
  __shared__ float lC[16 * XPX];
  __shared__ float lxc[16 * XPX];
  __shared__ float low[128];
  const int tid = threadIdx.x;
  const int px = tid >> 4;
  const int d = tid & 15;
  const int gp0 = blockIdx.x * 16;
  const int b = gp0 / Lk;
  const int l0 = gp0 - b * Lk;
  for (int i = tid; i < 1024; i += 256) {
    int c = i >> 4, pp = i & 15;
    lx[pp * 68 + c] = x[((size_t)(b * 64 + c)) * Lk + l0 + pp];
  }
  for (int i = tid; i < 528; i += 256) lxw[(i / 16) * 20 + (i % 16)] = xw[i];
  if (tid < 128) low[tid] = ow[tid];
  __syncthreads();
  float riw[8], riz[8];
#pragma unroll
  for (int g = 0; g < 8; ++g) {
    riw[g] = in_w[d * 8 + g];
    riz[g] = in_w[(16 + d) * 8 + g];
  }
  const float w0 = cw[d * 4 + 0], w1 = cw[d * 4 + 1], w2 = cw[d * 4 + 2],
              w3 = cw[d * 4 + 3], cbv = cb[d];
  const float dtwv = dtw[d], dtbv = dtb[d], Dv = Dp[d];
  float A2[16];
#pragma unroll
  for (int n = 0; n < 16; ++n) A2[n] = -__expf(Alog[d * 16 + n]);
  // in-projection + z-gate
  float xcr[8], zq[8];
#pragma unroll
  for (int tt = 0; tt < 8; ++tt) {
    float a = 0.f, zz = 0.f;
#pragma unroll
    for (int g = 0; g < 8; ++g) {
      float xv = lx[px * 68 + tt * 8 + g];
      a += xv * riw[g];
      zz += xv * riz[g];
    }
    xcr[tt] = a;
    zq[tt] = siluf(zz);
  }
  // causal conv k=4 + silu
  float xcq[8];
#pragma unroll
  for (int tt = 0; tt < 8; ++tt) {
    float s = cbv + w3 * xcr[tt];
    if (tt >= 1) s += w2 * xcr[tt - 1];
    if (tt >= 2) s += w1 * xcr[tt - 2];
    if (tt >= 3) s += w0 * xcr[tt - 3];
    xcq[tt] = siluf(s);
  }
#pragma unroll
  for (int tt = 0; tt < 8; ++tt) lxc[px * XPX + tt * XT + d] = xcq[tt];
  __syncthreads();
  // B, C (thread d computes state-index n = d), dt
  float dtv[8];
#pragma unroll
  for (int tt = 0; tt < 8; ++tt) {
    float sB = 0.f, sC = 0.f, ss = 0.f;
#pragma unroll
    for (int dd = 0; dd < 16; ++dd) {
      float xv = lxc[px * XPX + tt * XT + dd];
      ss += xv * lxw[dd];
      sB += xv * lxw[(1 + d) * 20 + dd];
      sC += xv * lxw[(17 + d) * 20 + dd];
    }
    lB[px * XPX + tt * XT + d] = sB;
    lC[px * XPX + tt * XT + d] = sC;
    dtv[tt] = softplusf(ss * dtwv + dtbv);
  }
  __syncthreads();
  // selective scan over 8 tokens
  float h[16];
#pragma unroll
  for (int n = 0; n < 16; ++n) h[n] = 0.f;
  float yv[8];
#pragma unroll
  for (int tt = 0; tt < 8; ++tt) {
    float u = dtv[tt] * xcq[tt];
    float acc = 0.f;
#pragma unroll
    for (int n = 0; n < 16; ++n) {
      float dA = __expf(dtv[tt] * A2[n]);
      h[n] = dA * h[n] + u * lB[px * XPX + tt * XT + n];
      acc += h[n] * lC[px * XPX + tt * XT + n];
    }
    yv[tt] = (acc + xcq[tt] * Dv) * zq[tt];
  }
#pragma unroll
  for (int tt = 0; tt < 8; ++tt) lxc[px * XPX + tt * XT + d] = yv[tt];
  __syncthreads();
  // out-projection 16 -> 8; thread handles outputs o = d*4 .. d*4+3
#pragma unroll
  for (int k = 0; k < 4; ++k) {
    int o = d * 4 + k;
    int tt = o >> 3, e = o & 7;
    float acc = 0.f;
#pragma unroll
    for (int dd = 0; dd < 16; ++dd)
      acc += lxc[px * XPX + tt * XT + dd] * low[e * 16 + dd];
    spe_y[((size_t)(b * 64 + tt * 8 + e)) * Lk + l0 + px] = acc;
  }
}

// ---------------- K6a: GN partial sums ----------------
// grid 256: gid = bx>>3 (32 groups: branch*16 + b*4 + g), part = bx&7
__global__ __launch_bounds__(256) void k_stats1(const float* __restrict__ spa_y,
                                                const float* __restrict__ spe_y,
                                                float* __restrict__ part) {
  const int gid = blockIdx.x >> 3;
  const int pi = blockIdx.x & 7;
  const int branch = gid >> 4;
  const int rem = gid & 15;
  const int b = rem >> 2;
  const int g = rem & 3;
  const float* src = (branch ? spe_y : spa_y) +
                     ((size_t)(b * 64 + g * 16)) * Lk + (size_t)pi * 18432;
  float s = 0.f, sq = 0.f;
  for (int i = 0; i < 18; ++i) {
    float4 v = *(const float4*)(src + (i * 256 + threadIdx.x) * 4);
    s += v.x + v.y + v.z + v.w;
    sq += v.x * v.x + v.y * v.y + v.z * v.z + v.w * v.w;
  }
  for (int off = 32; off > 0; off >>= 1) {
    s += __shfl_down(s, off);
    sq += __shfl_down(sq, off);
  }
  __shared__ float red[8];
  const int wid = threadIdx.x >> 6;
  if ((threadIdx.x & 63) == 0) { red[wid * 2] = s; red[wid * 2 + 1] = sq; }
  __syncthreads();
  if (threadIdx.x == 0) {
    s = red[0] + red[2] + red[4] + red[6];
    sq = red[1] + red[3] + red[5] + red[7];
    part[blockIdx.x * 2] = s;
    part[blockIdx.x * 2 + 1] = sq;
  }
}

// ---------------- K6b: finalize stats + fuse softmax ----------------
__global__ void k_stats2(const float* __restrict__ part, const float* __restrict__ fw,
                         float* __restrict__ stats) {
  const int t = threadIdx.x;
  if (t < 32) {
    float s = 0.f, sq = 0.f;
    for (int pi = 0; pi < 8; ++pi) {
      s += part[(t * 8 + pi) * 2];
      sq += part[(t * 8 + pi) * 2 + 1];
    }
    const float inv = 1.f / 147456.f;
    float m = s * inv;
    float var = sq * inv - m * m;
    stats[t * 2] = m;
    stats[t * 2 + 1] = 1.f / sqrtf(var + 1e-5f);
  } else if (t == 32) {
    float e0 = __expf(fw[0]), e1 = __expf(fw[1]);
    float inv = 1.f / (e0 + e1);
    stats[64] = e0 * inv;
    stats[65] = e1 * inv;
  }
}

// ---------------- K7: GN-affine + silu (both branches) + fusion + residual ----
// grid 256 (one block per (b,c) row), block 256
__global__ __launch_bounds__(256) void k_final(const float* __restrict__ spa_y,
                                               const float* __restrict__ spe_y,
                                               const float* __restrict__ x,
                                               const float* __restrict__ gga,
                                               const float* __restrict__ gba,
                                               const float* __restrict__ gge,
                                               const float* __restrict__ gbe,
                                               const float* __restrict__ stats,
                                               float* __restrict__ out) {
  const int bc = blockIdx.x;
  const int b = bc >> 6;
  const int c = bc & 63;
  const int g = c >> 4;
  const float w0 = stats[64], w1 = stats[65];
  const float m0 = stats[(b * 4 + g) * 2], r0 = stats[(b * 4 + g) * 2 + 1];
  const float m1 = stats[(16 + b * 4 + g) * 2], r1 = stats[(16 + b * 4 + g) * 2 + 1];
  const float ka = r0 * gga[c], ca = gba[c] - m0 * ka;
  const float ke = r1 * gge[c], ce = gbe[c] - m1 * ke;
  const size_t base = (size_t)bc * Lk;
  for (int i = 0; i < 9; ++i) {
    const int idx = (i * 256 + threadIdx.x) * 4;
    float4 a = *(const float4*)(spa_y + base + idx);
    float4 e = *(const float4*)(spe_y + base + idx);
    float4 xv = *(const float4*)(x + base + idx);
    float4 o;
    o.x = xv.x + w0 * siluf(a.x * ka + ca) + w1 * siluf(e.x * ke + ce);
    o.y = xv.y + w0 * siluf(a.y * ka + ca) + w1 * siluf(e.y * ke + ce);
    o.z = xv.z + w0 * siluf(a.z * ka + ca) + w1 * siluf(e.z * ke + ce);
    o.w = xv.w + w0 * siluf(a.w * ka + ca) + w1 * siluf(e.w * ke + ce);
    *(float4*)(out + base + idx) = o;
  }
}

// ---------------- launch ----------------
extern "C" void kernel_launch(void* const* d_in, const int* in_sizes, int n_in,
                              void* d_out, int out_size, void* d_ws, size_t ws_size,
                              hipStream_t stream) {
  (void)in_sizes; (void)n_in; (void)out_size; (void)ws_size;
  const float* x = (const float*)d_in[0];
  const float* spa_in_w = (const float*)d_in[1];
  const float* spa_conv_w = (const float*)d_in[2];
  const float* spa_conv_b = (const float*)d_in[3];
  const float* spa_x_w = (const float*)d_in[4];
  const float* spa_dt_w = (const float*)d_in[5];
  const float* spa_dt_b = (const float*)d_in[6];
  const float* spa_A_log = (const float*)d_in[7];
  const float* spa_D = (const float*)d_in[8];
  const float* spa_out_w = (const float*)d_in[9];
  const float* spa_gn_g = (const float*)d_in[10];
  const float* spa_gn_b = (const float*)d_in[11];
  const float* spe_in_w = (const float*)d_in[12];
  const float* spe_conv_w = (const float*)d_in[13];
  const float* spe_conv_b = (const float*)d_in[14];
  const float* spe_x_w = (const float*)d_in[15];
  const float* spe_dt_w = (const float*)d_in[16];
  const float* spe_dt_b = (const float*)d_in[17];
  const float* spe_A_log = (const float*)d_in[18];
  const float* spe_D = (const float*)d_in[19];
  const float* spe_out_w = (const float*)d_in[20];
  const float* spe_gn_g = (const float*)d_in[21];
  const float* spe_gn_b = (const float*)d_in[22];
  const float* fuse_w = (const float*)d_in[23];
  float* out = (float*)d_out;
  float* ws = (float*)d_ws;

  float* xz = ws;                         // 4*256*9216 = 9437184
  float* xc = xz + 9437184;               // 4718592
  float* xdbl = xc + 4718592;             // 4*9216*40 = 1474560
  float* gi = xdbl + 1474560;             // 4718592
  float* Pb = gi + 4718592;               // 1048576
  float* Hb = Pb + 1048576;               // 1048576
  float* Ib = Hb + 1048576;               // 1048576
  float* spa_y = Ib + 1048576;            // 2359296
  float* spe_y = spa_y + 2359296;         // 2359296
  float* part = spe_y + 2359296;          // 512
  float* stats = part + 512;              // 66

  k_inproj<<<dim3(144, 4), 256, 0, stream>>>(x, spa_in_w, xz);
  k_conv<<<dim3(9, 512), 256, 0, stream>>>(xz, spa_conv_w, spa_conv_b, xc);
  k_xdbl<<<576, 256, 0, stream>>>(xc, spa_x_w, xdbl);
  k_scan1<<<256, 256, 0, stream>>>(xdbl, xc, spa_A_log, spa_dt_w, spa_dt_b, Pb, Hb);
  k_scan2<<<32, 256, 0, stream>>>(Pb, Hb, Ib);
  k_scan3<<<256, 256, 0, stream>>>(xdbl, xc, xz, spa_A_log, spa_dt_w, spa_dt_b,
                                   spa_D, Ib, gi);
  k_out<<<576, 256, 0, stream>>>(gi, spa_out_w, spa_y);
  k_spe<<<2304, 256, 0, stream>>>(x, spe_in_w, spe_conv_w, spe_conv_b, spe_x_w,
                                  spe_dt_w, spe_dt_b, spe_A_log, spe_D, spe_out_w,
                                  spe_y);
  k_stats1<<<256, 256, 0, stream>>>(spa_y, spe_y, part);
  k_stats2<<<1, 64, 0, stream>>>(part, fuse_w, stats);
  k_final<<<256, 256, 0, stream>>>(spa_y, spe_y, x, spa_gn_g, spa_gn_b,
                                   spe_gn_g, spe_gn_b, stats, out);
}